// Round 5
// baseline (5020.239 us; speedup 1.0000x reference)
//
#include <hip/hip_runtime.h>

// LSTM: B=64, T=512, D=512, H=1024, G=4H=4096
// d_out: output[64][512][1024] fp32, then h_last[64][1024], c_last[64][1024]

typedef __attribute__((ext_vector_type(4))) float f32x4;
typedef __attribute__((ext_vector_type(4))) unsigned u32x4;
typedef __attribute__((ext_vector_type(8))) __bf16 bf16x8;
typedef __attribute__((ext_vector_type(4))) __bf16 bf16x4;

__device__ __forceinline__ f32x4 mfma16(bf16x8 a, bf16x8 b, f32x4 c) {
  return __builtin_amdgcn_mfma_f32_16x16x32_bf16(a, b, c, 0, 0, 0);
}
__device__ __forceinline__ float sigm(float x) {
  return __builtin_amdgcn_rcpf(1.0f + __expf(-x));
}
__device__ __forceinline__ float tanh_(float x) {
  return 2.0f * __builtin_amdgcn_rcpf(1.0f + __expf(-2.0f * x)) - 1.0f;
}
__device__ __forceinline__ unsigned umin2(unsigned a, unsigned b) { return a < b ? a : b; }

// ---------- Phase 1: gates[t][g][b] = sum_d W_ih[g,d]*x[b,t,d] + b_ih[g] + b_hh[g]
template<bool GF32>
__global__ __launch_bounds__(256) void k_gates(
    const float* __restrict__ x, const float* __restrict__ Wih,
    const float* __restrict__ bih, const float* __restrict__ bhh,
    void* __restrict__ gates)
{
  __shared__ __align__(16) __bf16 lA[128][40];
  __shared__ __align__(16) __bf16 lB[128][40];
  int bid = blockIdx.x;
  int grp = bid >> 9;
  int rem = bid & 511;
  int mt = rem & 31;
  int nt = (grp << 4) + (rem >> 5);
  const int m0 = mt << 7, n0 = nt << 7;
  const int tid = threadIdx.x, lane = tid & 63, wave = tid >> 6;
  const int cl = lane & 15, rg = lane >> 4;
  const int wm = (wave >> 1) << 6, wn = (wave & 1) << 6;
  f32x4 acc[4][4] = {};

  const int r = tid >> 1;
  const int kh = (tid & 1) << 4;
  const float* aSrc = Wih + (size_t)(m0 + r) * 512 + kh;
  const int nn = n0 + r;
  const float* bSrc = x + ((size_t)(nn & 63) * 512 + (nn >> 6)) * 512 + kh;

  for (int k0 = 0; k0 < 512; k0 += 32) {
    __syncthreads();
    #pragma unroll
    for (int i = 0; i < 16; i += 4) {
      f32x4 va = *(const f32x4*)(aSrc + k0 + i);
      f32x4 vb = *(const f32x4*)(bSrc + k0 + i);
      bf16x4 pa, pb;
      #pragma unroll
      for (int j = 0; j < 4; ++j) { pa[j] = (__bf16)va[j]; pb[j] = (__bf16)vb[j]; }
      *(bf16x4*)&lA[r][kh + i] = pa;
      *(bf16x4*)&lB[r][kh + i] = pb;
    }
    __syncthreads();
    bf16x8 afr[4], bfr[4];
    #pragma unroll
    for (int q = 0; q < 4; ++q) {
      afr[q] = *(const bf16x8*)&lA[wm + q * 16 + cl][rg * 8];
      bfr[q] = *(const bf16x8*)&lB[wn + q * 16 + cl][rg * 8];
    }
    #pragma unroll
    for (int mi = 0; mi < 4; ++mi)
      #pragma unroll
      for (int ni = 0; ni < 4; ++ni)
        acc[mi][ni] = mfma16(afr[mi], bfr[ni], acc[mi][ni]);
  }

  #pragma unroll
  for (int mi = 0; mi < 4; ++mi) {
    int gb = m0 + wm + mi * 16 + rg * 4;
    f32x4 bsum = *(const f32x4*)(bih + gb);
    bsum += *(const f32x4*)(bhh + gb);
    #pragma unroll
    for (int ni = 0; ni < 4; ++ni) {
      int n = n0 + wn + ni * 16 + cl;
      int tt = n >> 6, bb = n & 63;
      #pragma unroll
      for (int v = 0; v < 4; ++v) {
        float val = acc[mi][ni][v] + bsum[v];
        size_t idx = ((size_t)tt * 4096 + (size_t)(gb + v)) * 64 + bb;
        if (GF32) ((float*)gates)[idx] = val;
        else      ((__bf16*)gates)[idx] = (__bf16)val;
      }
    }
  }
}

// ---------- Phase 2: persistent recurrence, BARRIER-FREE.
// 128 blocks x 4 waves = 512 independent waves. Per step, each wave:
//   poll 512 per-wave tags (sc0 sc1, LLC) until min >= t
//   load h_t fragments (sc0 sc1) -> MFMA vs W_hh frags in LDS
//   elementwise -> store h slice (sc0 sc1) -> vmcnt(0) -> store tag t+1
//   out NT-stores + gates prefetch issued AFTER tag (drain during next poll)
template<bool GF32>
__global__ __launch_bounds__(256, 1) void k_rnn(
    const void* __restrict__ gates, const float* __restrict__ Whh,
    __bf16* __restrict__ hA, __bf16* __restrict__ hB,
    unsigned* __restrict__ tags,
    float* __restrict__ out, float* __restrict__ hlast, float* __restrict__ clast)
{
  __shared__ __align__(16) __bf16 WF[2 * 32 * 64 * 8];  // 64 KB
  const int tid = threadIdx.x, lane = tid & 63, wave = tid >> 6;
  const int cl = lane & 15, rg = lane >> 4;
  const int hb = blockIdx.x << 3;   // 8 hidden units
  const int bo = wave << 4;         // batch offset
  const int bb = bo + rg * 4;       // base batch for acc rows
  const int wid = (blockIdx.x << 2) + wave;  // 0..511

  int wrowA[2];
  #pragma unroll
  for (int nt = 0; nt < 2; ++nt) {
    int nl = nt * 16 + cl;
    wrowA[nt] = (nl >> 3) * 1024 + hb + (nl & 7);
  }

  if (wave == 0) {
    #pragma unroll
    for (int nt = 0; nt < 2; ++nt) {
      const float* wsrc = Whh + (size_t)wrowA[nt] * 1024 + rg * 8;
      for (int kt = 0; kt < 32; ++kt) {
        f32x4 lo = *(const f32x4*)(wsrc + kt * 32);
        f32x4 hi = *(const f32x4*)(wsrc + kt * 32 + 4);
        bf16x8 f;
        #pragma unroll
        for (int j = 0; j < 4; ++j) { f[j] = (__bf16)lo[j]; f[4 + j] = (__bf16)hi[j]; }
        *(bf16x8*)&WF[(((size_t)nt * 32 + kt) * 64 + lane) * 8] = f;
      }
    }
  }
  __syncthreads();

  float cst[4] = {0.f, 0.f, 0.f, 0.f};

  f32x4 gp[2];
  #pragma unroll
  for (int nt = 0; nt < 2; ++nt) {
    size_t idx = (size_t)wrowA[nt] * 64 + bb;
    if (GF32) gp[nt] = *(const f32x4*)((const float*)gates + idx);
    else {
      bf16x4 q = *(const bf16x4*)((const __bf16*)gates + idx);
      #pragma unroll
      for (int j = 0; j < 4; ++j) gp[nt][j] = (float)q[j];
    }
  }

  for (int t = 0; t < 512; ++t) {
    // ---- poll tags (skip at t=0: h_0 = 0, no h term)
    if (t) {
      const unsigned* tp = tags + (lane << 3);
      for (;;) {
        u32x4 ta, tb;
        asm volatile(
          "global_load_dwordx4 %0, %2, off sc0 sc1\n\t"
          "global_load_dwordx4 %1, %2, off offset:16 sc0 sc1"
          : "=v"(ta), "=v"(tb) : "v"(tp) : "memory");
        asm volatile("s_waitcnt vmcnt(0)" ::: "memory");
        __builtin_amdgcn_sched_barrier(0);
        unsigned m = umin2(umin2(umin2(ta[0], ta[1]), umin2(ta[2], ta[3])),
                           umin2(umin2(tb[0], tb[1]), umin2(tb[2], tb[3])));
        if (__all((int)(m >= (unsigned)t))) break;
        __builtin_amdgcn_s_sleep(2);
      }
    }

    f32x4 acc0 = gp[0], acc1 = gp[1];

    // ---- h_t @ W_hh^T (skip at t=0)
    if (t) {
      const __bf16* hsrc = (t & 1) ? hB : hA;  // h_t lives in buf[t&1]
      const __bf16* hrow = hsrc + (size_t)(bo + cl) * 1024 + rg * 8;
      bf16x8 af[32];
      #pragma unroll
      for (int kt = 0; kt < 32; ++kt)
        asm volatile("global_load_dwordx4 %0, %1, off offset:%2 sc0 sc1"
                     : "=v"(af[kt]) : "v"(hrow), "i"(kt * 64) : "memory");
      asm volatile("s_waitcnt vmcnt(16)" ::: "memory");  // oldest 16 done
      __builtin_amdgcn_sched_barrier(0);
      #pragma unroll
      for (int kt = 0; kt < 16; ++kt) {
        acc0 = mfma16(af[kt], *(const bf16x8*)&WF[((size_t)kt * 64 + lane) * 8], acc0);
        acc1 = mfma16(af[kt], *(const bf16x8*)&WF[((size_t)(32 + kt) * 64 + lane) * 8], acc1);
      }
      asm volatile("s_waitcnt vmcnt(0)" ::: "memory");
      __builtin_amdgcn_sched_barrier(0);
      #pragma unroll
      for (int kt = 16; kt < 32; ++kt) {
        acc0 = mfma16(af[kt], *(const bf16x8*)&WF[((size_t)kt * 64 + lane) * 8], acc0);
        acc1 = mfma16(af[kt], *(const bf16x8*)&WF[((size_t)(32 + kt) * 64 + lane) * 8], acc1);
      }
    }

    // ---- elementwise: acc0 = {i | f}, acc1 = {g | o}; pair via xor-8
    f32x4 a0s, a1s;
    #pragma unroll
    for (int j = 0; j < 4; ++j) {
      a0s[j] = __shfl_xor(acc0[j], 8, 64);
      a1s[j] = __shfl_xor(acc1[j], 8, 64);
    }
    float hv[4], cc[4];
    #pragma unroll
    for (int v = 0; v < 4; ++v) {
      float iv = sigm(acc0[v]);
      float fv = sigm(a0s[v]);
      float gv = tanh_(acc1[v]);
      float ov = sigm(a1s[v]);
      float c = fv * cst[v] + iv * gv;
      cst[v] = c;
      hv[v] = ov * tanh_(c);
      cc[v] = c;
    }

    // ---- store h_{t+1} slice to buf[(t+1)&1] via LLC write-through
    __bf16* hnext = (t & 1) ? hA : hB;
    #pragma unroll
    for (int v = 0; v < 4; ++v) {
      union { __bf16 b; unsigned short s; } cvt;
      cvt.b = (__bf16)hv[v];
      int me = cvt.s;
      int nb = __shfl_xor(me, 1, 64);
      if (cl < 8 && (cl & 1) == 0) {
        unsigned word = (unsigned)(me & 0xffff) | ((unsigned)(nb & 0xffff) << 16);
        unsigned* p = (unsigned*)hnext + (((size_t)(bb + v)) << 9) + ((hb + cl) >> 1);
        asm volatile("global_store_dword %0, %1, off sc0 sc1"
                     :: "v"(p), "v"(word) : "memory");
      }
    }
    // drain h stores to the coherence point, then publish tag t+1
    asm volatile("s_waitcnt vmcnt(0)" ::: "memory");
    if (lane == 0) {
      unsigned tv = (unsigned)(t + 1);
      unsigned* tp = tags + wid;
      asm volatile("global_store_dword %0, %1, off sc0 sc1"
                   :: "v"(tp), "v"(tv) : "memory");
    }

    // ---- off-critical-path: out stores + next-step gates prefetch
    if (cl < 8) {
      #pragma unroll
      for (int v = 0; v < 4; ++v) {
        int b = bb + v;
        __builtin_nontemporal_store(hv[v], &out[((size_t)b * 512 + t) * 1024 + hb + cl]);
        if (t == 511) {
          __builtin_nontemporal_store(hv[v], &hlast[(size_t)b * 1024 + hb + cl]);
          __builtin_nontemporal_store(cc[v], &clast[(size_t)b * 1024 + hb + cl]);
        }
      }
    }
    if (t < 511) {
      #pragma unroll
      for (int nt = 0; nt < 2; ++nt) {
        size_t idx = ((size_t)(t + 1) * 4096 + (size_t)wrowA[nt]) * 64 + bb;
        if (GF32) gp[nt] = *(const f32x4*)((const float*)gates + idx);
        else {
          bf16x4 q = *(const bf16x4*)((const __bf16*)gates + idx);
          #pragma unroll
          for (int j = 0; j < 4; ++j) gp[nt][j] = (float)q[j];
        }
      }
    }
  }
}

extern "C" void kernel_launch(void* const* d_in, const int* in_sizes, int n_in,
                              void* d_out, int out_size, void* d_ws, size_t ws_size,
                              hipStream_t stream) {
  const float* x   = (const float*)d_in[0];
  const float* Wih = (const float*)d_in[1];
  const float* bih = (const float*)d_in[2];
  const float* Whh = (const float*)d_in[3];
  const float* bhh = (const float*)d_in[4];
  float* out   = (float*)d_out;
  float* hlast = out + (size_t)64 * 512 * 1024;
  float* clast = hlast + (size_t)64 * 1024;

  char* ws = (char*)d_ws;
  unsigned* tags = (unsigned*)ws;                 // 512 per-wave tags (2 KB)
  __bf16* hA = (__bf16*)(ws + 4096);
  __bf16* hB = (__bf16*)(ws + 4096 + 131072);
  void* gates = (void*)(ws + (1 << 20));
  const size_t need_f32 = (size_t)(1 << 20) + (size_t)512 * 4096 * 64 * 4;
  bool gf32 = (ws_size >= need_f32);

  hipMemsetAsync(tags, 0, 2048, stream);  // stale/poisoned tags would deadlock
                                          // or (0xAA) instantly pass — must zero

  if (gf32) {
    k_gates<true><<<8192, 256, 0, stream>>>(x, Wih, bih, bhh, gates);
    k_rnn<true><<<128, 256, 0, stream>>>(gates, Whh, hA, hB, tags, out, hlast, clast);
  } else {
    k_gates<false><<<8192, 256, 0, stream>>>(x, Wih, bih, bhh, gates);
    k_rnn<false><<<128, 256, 0, stream>>>(gates, Whh, hA, hB, tags, out, hlast, clast);
  }
}

// Round 6
// 3838.249 us; speedup vs baseline: 1.3080x; 1.3080x over previous
//
#include <hip/hip_runtime.h>

// LSTM: B=64, T=512, D=512, H=1024, G=4H=4096
// d_out: output[64][512][1024] fp32, then h_last[64][1024], c_last[64][1024]

typedef __attribute__((ext_vector_type(4))) float f32x4;
typedef __attribute__((ext_vector_type(4))) unsigned u32x4;
typedef __attribute__((ext_vector_type(8))) __bf16 bf16x8;
typedef __attribute__((ext_vector_type(4))) __bf16 bf16x4;

__device__ __forceinline__ f32x4 mfma16(bf16x8 a, bf16x8 b, f32x4 c) {
  return __builtin_amdgcn_mfma_f32_16x16x32_bf16(a, b, c, 0, 0, 0);
}
__device__ __forceinline__ float sigm(float x) {
  return __builtin_amdgcn_rcpf(1.0f + __expf(-x));
}
__device__ __forceinline__ float tanh_(float x) {
  return 2.0f * __builtin_amdgcn_rcpf(1.0f + __expf(-2.0f * x)) - 1.0f;
}
__device__ __forceinline__ unsigned umin2(unsigned a, unsigned b) { return a < b ? a : b; }

// ---------- Phase 1: gates[t][g][b] = sum_d W_ih[g,d]*x[b,t,d] + b_ih[g] + b_hh[g]
template<bool GF32>
__global__ __launch_bounds__(256) void k_gates(
    const float* __restrict__ x, const float* __restrict__ Wih,
    const float* __restrict__ bih, const float* __restrict__ bhh,
    void* __restrict__ gates)
{
  __shared__ __align__(16) __bf16 lA[128][40];
  __shared__ __align__(16) __bf16 lB[128][40];
  int bid = blockIdx.x;
  int grp = bid >> 9;
  int rem = bid & 511;
  int mt = rem & 31;
  int nt = (grp << 4) + (rem >> 5);
  const int m0 = mt << 7, n0 = nt << 7;
  const int tid = threadIdx.x, lane = tid & 63, wave = tid >> 6;
  const int cl = lane & 15, rg = lane >> 4;
  const int wm = (wave >> 1) << 6, wn = (wave & 1) << 6;
  f32x4 acc[4][4] = {};

  const int r = tid >> 1;
  const int kh = (tid & 1) << 4;
  const float* aSrc = Wih + (size_t)(m0 + r) * 512 + kh;
  const int nn = n0 + r;
  const float* bSrc = x + ((size_t)(nn & 63) * 512 + (nn >> 6)) * 512 + kh;

  for (int k0 = 0; k0 < 512; k0 += 32) {
    __syncthreads();
    #pragma unroll
    for (int i = 0; i < 16; i += 4) {
      f32x4 va = *(const f32x4*)(aSrc + k0 + i);
      f32x4 vb = *(const f32x4*)(bSrc + k0 + i);
      bf16x4 pa, pb;
      #pragma unroll
      for (int j = 0; j < 4; ++j) { pa[j] = (__bf16)va[j]; pb[j] = (__bf16)vb[j]; }
      *(bf16x4*)&lA[r][kh + i] = pa;
      *(bf16x4*)&lB[r][kh + i] = pb;
    }
    __syncthreads();
    bf16x8 afr[4], bfr[4];
    #pragma unroll
    for (int q = 0; q < 4; ++q) {
      afr[q] = *(const bf16x8*)&lA[wm + q * 16 + cl][rg * 8];
      bfr[q] = *(const bf16x8*)&lB[wn + q * 16 + cl][rg * 8];
    }
    #pragma unroll
    for (int mi = 0; mi < 4; ++mi)
      #pragma unroll
      for (int ni = 0; ni < 4; ++ni)
        acc[mi][ni] = mfma16(afr[mi], bfr[ni], acc[mi][ni]);
  }

  #pragma unroll
  for (int mi = 0; mi < 4; ++mi) {
    int gb = m0 + wm + mi * 16 + rg * 4;
    f32x4 bsum = *(const f32x4*)(bih + gb);
    bsum += *(const f32x4*)(bhh + gb);
    #pragma unroll
    for (int ni = 0; ni < 4; ++ni) {
      int n = n0 + wn + ni * 16 + cl;
      int tt = n >> 6, bb = n & 63;
      #pragma unroll
      for (int v = 0; v < 4; ++v) {
        float val = acc[mi][ni][v] + bsum[v];
        size_t idx = ((size_t)tt * 4096 + (size_t)(gb + v)) * 64 + bb;
        if (GF32) ((float*)gates)[idx] = val;
        else      ((__bf16*)gates)[idx] = (__bf16)val;
      }
    }
  }
}

// ---------- Phase 2: persistent recurrence, barrier-free per-wave tags.
// Key scheduling invariant: nothing but the 2 tag loads is ever outstanding
// when the poll's vmcnt(0) runs. out-stores of step t-1 and gates prefetch of
// step t+1 are issued AFTER step t's h-loads and drain in the shadow of
// MFMA + elementwise (counted waits: vmcnt(20) / vmcnt(6)).
template<bool GF32>
__global__ __launch_bounds__(256, 1) void k_rnn(
    const void* __restrict__ gates, const float* __restrict__ Whh,
    __bf16* __restrict__ hA, __bf16* __restrict__ hB,
    unsigned* __restrict__ tags,
    float* __restrict__ out, float* __restrict__ hlast, float* __restrict__ clast)
{
  __shared__ __align__(16) __bf16 WF[2 * 32 * 64 * 8];  // 64 KB
  const int tid = threadIdx.x, lane = tid & 63, wave = tid >> 6;
  const int cl = lane & 15, rg = lane >> 4;
  const int hb = blockIdx.x << 3;   // 8 hidden units
  const int bo = wave << 4;         // batch offset
  const int bb = bo + rg * 4;       // base batch for acc rows
  const int wid = (blockIdx.x << 2) + wave;  // 0..511

  int wrowA[2];
  #pragma unroll
  for (int nt = 0; nt < 2; ++nt) {
    int nl = nt * 16 + cl;
    wrowA[nt] = (nl >> 3) * 1024 + hb + (nl & 7);
  }

  if (wave == 0) {
    #pragma unroll
    for (int nt = 0; nt < 2; ++nt) {
      const float* wsrc = Whh + (size_t)wrowA[nt] * 1024 + rg * 8;
      for (int kt = 0; kt < 32; ++kt) {
        f32x4 lo = *(const f32x4*)(wsrc + kt * 32);
        f32x4 hi = *(const f32x4*)(wsrc + kt * 32 + 4);
        bf16x8 f;
        #pragma unroll
        for (int j = 0; j < 4; ++j) { f[j] = (__bf16)lo[j]; f[4 + j] = (__bf16)hi[j]; }
        *(bf16x8*)&WF[(((size_t)nt * 32 + kt) * 64 + lane) * 8] = f;
      }
    }
  }
  __syncthreads();

  float cst[4] = {0.f, 0.f, 0.f, 0.f};
  float hvp[4] = {0.f, 0.f, 0.f, 0.f};   // previous step's h (deferred out store)

  f32x4 gp[2];
  #pragma unroll
  for (int nt = 0; nt < 2; ++nt) {
    size_t idx = (size_t)wrowA[nt] * 64 + bb;
    if (GF32) gp[nt] = *(const f32x4*)((const float*)gates + idx);
    else {
      bf16x4 q = *(const bf16x4*)((const __bf16*)gates + idx);
      #pragma unroll
      for (int j = 0; j < 4; ++j) gp[nt][j] = (float)q[j];
    }
  }

  for (int t = 0; t < 512; ++t) {
    // ---- A: poll tags (skip at t=0). Only the 2 tag loads are outstanding.
    if (t) {
      const unsigned* tp = tags + (lane << 3);
      for (;;) {
        u32x4 ta, tb;
        asm volatile(
          "global_load_dwordx4 %0, %2, off sc0 sc1\n\t"
          "global_load_dwordx4 %1, %2, off offset:16 sc0 sc1"
          : "=v"(ta), "=v"(tb) : "v"(tp) : "memory");
        asm volatile("s_waitcnt vmcnt(0)" ::: "memory");
        __builtin_amdgcn_sched_barrier(0);
        unsigned m = umin2(umin2(umin2(ta[0], ta[1]), umin2(ta[2], ta[3])),
                           umin2(umin2(tb[0], tb[1]), umin2(tb[2], tb[3])));
        if (__all((int)(m >= (unsigned)t))) break;
        __builtin_amdgcn_s_sleep(1);
      }
    }

    f32x4 acc0 = gp[0], acc1 = gp[1];

    // ---- B: issue h_t loads (oldest in the vmcnt queue)
    bf16x8 af[32];
    if (t) {
      const __bf16* hsrc = (t & 1) ? hB : hA;  // h_t lives in buf[t&1]
      const __bf16* hrow = hsrc + (size_t)(bo + cl) * 1024 + rg * 8;
      #pragma unroll
      for (int kt = 0; kt < 32; ++kt)
        asm volatile("global_load_dwordx4 %0, %1, off offset:%2 sc0 sc1"
                     : "=v"(af[kt]) : "v"(hrow), "i"(kt * 64) : "memory");
    }
    __builtin_amdgcn_sched_barrier(0);

    // ---- C: background ops — deferred out stores (t-1) + gates prefetch.
    // These drain during MFMA/elementwise, never under a blocking wait.
    if (t && cl < 8) {
      #pragma unroll
      for (int v = 0; v < 4; ++v)
        __builtin_nontemporal_store(
            hvp[v], &out[((size_t)(bb + v) * 512 + (t - 1)) * 1024 + hb + cl]);
    }
    {
      int tn = (t < 511) ? t + 1 : t;   // uniform issue count at t=511
      #pragma unroll
      for (int nt = 0; nt < 2; ++nt) {
        size_t idx = ((size_t)tn * 4096 + (size_t)wrowA[nt]) * 64 + bb;
        if (GF32) gp[nt] = *(const f32x4*)((const float*)gates + idx);
        else {
          bf16x4 q = *(const bf16x4*)((const __bf16*)gates + idx);
          #pragma unroll
          for (int j = 0; j < 4; ++j) gp[nt][j] = (float)q[j];
        }
      }
    }
    __builtin_amdgcn_sched_barrier(0);

    // ---- D: counted waits + MFMA (queue: 32 h oldest, then ~6 newer)
    if (t) {
      asm volatile("s_waitcnt vmcnt(20)" ::: "memory");  // h[0:16) complete
      __builtin_amdgcn_sched_barrier(0);
      #pragma unroll
      for (int kt = 0; kt < 16; ++kt) {
        acc0 = mfma16(af[kt], *(const bf16x8*)&WF[((size_t)kt * 64 + lane) * 8], acc0);
        acc1 = mfma16(af[kt], *(const bf16x8*)&WF[((size_t)(32 + kt) * 64 + lane) * 8], acc1);
      }
      asm volatile("s_waitcnt vmcnt(6)" ::: "memory");   // h[16:32) complete
      __builtin_amdgcn_sched_barrier(0);
      #pragma unroll
      for (int kt = 16; kt < 32; ++kt) {
        acc0 = mfma16(af[kt], *(const bf16x8*)&WF[((size_t)kt * 64 + lane) * 8], acc0);
        acc1 = mfma16(af[kt], *(const bf16x8*)&WF[((size_t)(32 + kt) * 64 + lane) * 8], acc1);
      }
    }

    // ---- E: elementwise: acc0 = {i | f}, acc1 = {g | o}; pair via xor-8
    f32x4 a0s, a1s;
    #pragma unroll
    for (int j = 0; j < 4; ++j) {
      a0s[j] = __shfl_xor(acc0[j], 8, 64);
      a1s[j] = __shfl_xor(acc1[j], 8, 64);
    }
    float hv[4];
    #pragma unroll
    for (int v = 0; v < 4; ++v) {
      float iv = sigm(acc0[v]);
      float fv = sigm(a0s[v]);
      float gv = tanh_(acc1[v]);
      float ov = sigm(a1s[v]);
      float c = fv * cst[v] + iv * gv;
      cst[v] = c;
      hv[v] = ov * tanh_(c);
    }

    // ---- F: h store -> full drain (everything had slack) -> tag publish
    __bf16* hnext = (t & 1) ? hA : hB;
    #pragma unroll
    for (int v = 0; v < 4; ++v) {
      union { __bf16 b; unsigned short s; } cvt;
      cvt.b = (__bf16)hv[v];
      int me = cvt.s;
      int nb = __shfl_xor(me, 1, 64);
      if (cl < 8 && (cl & 1) == 0) {
        unsigned word = (unsigned)(me & 0xffff) | ((unsigned)(nb & 0xffff) << 16);
        unsigned* p = (unsigned*)hnext + (((size_t)(bb + v)) << 9) + ((hb + cl) >> 1);
        asm volatile("global_store_dword %0, %1, off sc0 sc1"
                     :: "v"(p), "v"(word) : "memory");
      }
    }
    asm volatile("s_waitcnt vmcnt(0)" ::: "memory");
    if (lane == 0 && t < 511) {
      unsigned tv = (unsigned)(t + 1);
      unsigned* tp = tags + wid;
      asm volatile("global_store_dword %0, %1, off sc0 sc1"
                   :: "v"(tp), "v"(tv) : "memory");
    }

    #pragma unroll
    for (int v = 0; v < 4; ++v) hvp[v] = hv[v];
  }

  // ---- post-loop: out[t=511] + hlast + clast
  if (cl < 8) {
    #pragma unroll
    for (int v = 0; v < 4; ++v) {
      int b = bb + v;
      __builtin_nontemporal_store(hvp[v], &out[((size_t)b * 512 + 511) * 1024 + hb + cl]);
      __builtin_nontemporal_store(hvp[v], &hlast[(size_t)b * 1024 + hb + cl]);
      __builtin_nontemporal_store(cst[v], &clast[(size_t)b * 1024 + hb + cl]);
    }
  }
}

extern "C" void kernel_launch(void* const* d_in, const int* in_sizes, int n_in,
                              void* d_out, int out_size, void* d_ws, size_t ws_size,
                              hipStream_t stream) {
  const float* x   = (const float*)d_in[0];
  const float* Wih = (const float*)d_in[1];
  const float* bih = (const float*)d_in[2];
  const float* Whh = (const float*)d_in[3];
  const float* bhh = (const float*)d_in[4];
  float* out   = (float*)d_out;
  float* hlast = out + (size_t)64 * 512 * 1024;
  float* clast = hlast + (size_t)64 * 1024;

  char* ws = (char*)d_ws;
  unsigned* tags = (unsigned*)ws;                 // 512 per-wave tags (2 KB)
  __bf16* hA = (__bf16*)(ws + 4096);
  __bf16* hB = (__bf16*)(ws + 4096 + 131072);
  void* gates = (void*)(ws + (1 << 20));
  const size_t need_f32 = (size_t)(1 << 20) + (size_t)512 * 4096 * 64 * 4;
  bool gf32 = (ws_size >= need_f32);

  hipMemsetAsync(tags, 0, 2048, stream);  // must re-zero every call (0xAA poison)

  if (gf32) {
    k_gates<true><<<8192, 256, 0, stream>>>(x, Wih, bih, bhh, gates);
    k_rnn<true><<<128, 256, 0, stream>>>(gates, Whh, hA, hB, tags, out, hlast, clast);
  } else {
    k_gates<false><<<8192, 256, 0, stream>>>(x, Wih, bih, bhh, gates);
    k_rnn<false><<<128, 256, 0, stream>>>(gates, Whh, hA, hB, tags, out, hlast, clast);
  }
}